// Round 1
// baseline (625.705 us; speedup 1.0000x reference)
//
#include <hip/hip_runtime.h>
#include <hip/hip_fp16.h>

#define TT 512
#define BB 128
#define EE 128
#define HH 128
#define GG 512  // 4*H

typedef _Float16 half2_t __attribute__((ext_vector_type(2)));

__device__ __forceinline__ half2_t as_h2(unsigned int u) {
    return __builtin_bit_cast(half2_t, u);
}

__device__ __forceinline__ half2_t pack2(float x, float y) {
    half2_t r;
    r.x = (_Float16)x;
    r.y = (_Float16)y;
    return r;
}

__device__ __forceinline__ float fdot2(half2_t a, half2_t b, float c) {
#if __has_builtin(__builtin_amdgcn_fdot2)
    return __builtin_amdgcn_fdot2(a, b, c, false);
#else
    return c + (float)a.x * (float)b.x + (float)a.y * (float)b.y;
#endif
}

__device__ __forceinline__ float sigmoidf_fast(float x) {
    return 1.0f / (1.0f + __expf(-x));
}
__device__ __forceinline__ float tanhf_fast(float x) {
    return 2.0f / (1.0f + __expf(-2.0f * x)) - 1.0f;
}

// One block per (direction, batch element). 512 threads; thread g owns gate
// row g of Wih and Whh in packed-f16 registers (64+64 half2 = 128 VGPRs).
// Per timestep: g_pre = bias + Wih[g]·e_t + Whh[g]·h_{t-1} via v_dot2_f32_f16,
// activate, exchange gates through LDS, threads 0..127 update c/h and the
// running max over time. Input projection is fused (no xp materialization).
__global__ __launch_bounds__(512, 2) void bilstm_kernel(
    const int* __restrict__ x, const float* __restrict__ emb,
    const float* __restrict__ Wih_f, const float* __restrict__ Whh_f,
    const float* __restrict__ bih_f, const float* __restrict__ bhh_f,
    const float* __restrict__ Wih_b, const float* __restrict__ Whh_b,
    const float* __restrict__ bih_b, const float* __restrict__ bhh_b,
    float* __restrict__ pooled)
{
    const int tid = threadIdx.x;
    const int blk = blockIdx.x;
    const int b   = blk & (BB - 1);
    const int dir = blk >> 7;   // 0 = forward, 1 = backward

    const float* Wih = dir ? Wih_b : Wih_f;
    const float* Whh = dir ? Whh_b : Whh_f;
    const float* bih = dir ? bih_b : bih_f;
    const float* bhh = dir ? bhh_b : bhh_f;

    __shared__ __align__(16) _Float16 e_sm[2][EE];
    __shared__ __align__(16) _Float16 h_sm[HH];
    __shared__ float gates_sm[GG];
    __shared__ int   x_sm[TT];

    // ---- load this thread's weight rows into packed-f16 registers ----
    half2_t wih[64], whh[64];
    {
        const float4* wr = (const float4*)(Wih + (size_t)tid * EE);
        const float4* hr = (const float4*)(Whh + (size_t)tid * EE);
        #pragma unroll
        for (int q = 0; q < 32; ++q) {
            float4 a = wr[q];
            wih[2*q]   = pack2(a.x, a.y);
            wih[2*q+1] = pack2(a.z, a.w);
        }
        #pragma unroll
        for (int q = 0; q < 32; ++q) {
            float4 a = hr[q];
            whh[2*q]   = pack2(a.x, a.y);
            whh[2*q+1] = pack2(a.z, a.w);
        }
    }
    const float bias = bih[tid] + bhh[tid];

    // token ids for this batch row
    x_sm[tid] = x[(size_t)b * TT + tid];
    __syncthreads();

    // stage e for first step; init h = 0
    if (tid < EE) {
        int t0  = dir ? (TT - 1) : 0;
        int id0 = x_sm[t0];
        e_sm[0][tid] = (_Float16)emb[(size_t)id0 * EE + tid];
        h_sm[tid]    = (_Float16)0.0f;
    }
    __syncthreads();

    float c = 0.0f, hmax = -1e30f;

    for (int t = 0; t < TT; ++t) {
        const int buf = t & 1;

        // prefetch next timestep's embedding row (latency hidden by dots)
        float epre = 0.0f;
        if (tid < EE) {
            int tn  = (t + 1 < TT) ? (t + 1) : t;
            int tp  = dir ? (TT - 1 - tn) : tn;
            int idn = x_sm[tp];
            epre = emb[(size_t)idn * EE + tid];
        }

        // ---- two 128-length dot products via v_dot2_f32_f16 ----
        const uint4* ev = (const uint4*)e_sm[buf];
        const uint4* hv = (const uint4*)h_sm;
        float a0 = 0.0f, a1 = 0.0f, a2 = 0.0f, a3 = 0.0f;
        #pragma unroll
        for (int q = 0; q < 16; ++q) {
            uint4 e4 = ev[q];
            uint4 h4 = hv[q];
            a0 = fdot2(as_h2(e4.x), wih[4*q+0], a0);
            a1 = fdot2(as_h2(e4.y), wih[4*q+1], a1);
            a0 = fdot2(as_h2(e4.z), wih[4*q+2], a0);
            a1 = fdot2(as_h2(e4.w), wih[4*q+3], a1);
            a2 = fdot2(as_h2(h4.x), whh[4*q+0], a2);
            a3 = fdot2(as_h2(h4.y), whh[4*q+1], a3);
            a2 = fdot2(as_h2(h4.z), whh[4*q+2], a2);
            a3 = fdot2(as_h2(h4.w), whh[4*q+3], a3);
        }
        float pre = bias + ((a0 + a1) + (a2 + a3));

        // PyTorch gate order: [i | f | g | o]; sigmoid except g -> tanh.
        // Branch is wave-uniform (waves 4,5 take tanh).
        float act;
        if (tid < 256 || tid >= 384) act = sigmoidf_fast(pre);
        else                         act = tanhf_fast(pre);
        gates_sm[tid] = act;
        __syncthreads();

        if (tid < HH) {
            float ig = gates_sm[tid];
            float fg = gates_sm[HH + tid];
            float gg = gates_sm[2*HH + tid];
            float og = gates_sm[3*HH + tid];
            c = fg * c + ig * gg;
            float hval = og * tanhf_fast(c);
            hmax = fmaxf(hmax, hval);
            h_sm[tid] = (_Float16)hval;
            e_sm[1 - buf][tid] = (_Float16)epre;
        }
        __syncthreads();
    }

    if (tid < HH) {
        pooled[(size_t)b * 256 + dir * HH + tid] = hmax;
    }
}

// pooled (128,256) -> relu(W1 @ . + b1) -> sigmoid(W2 @ . + b2) -> out (128,1)
__global__ __launch_bounds__(64) void mlp_kernel(
    const float* __restrict__ pooled, const float* __restrict__ W1,
    const float* __restrict__ b1, const float* __restrict__ W2,
    const float* __restrict__ b2, float* __restrict__ out)
{
    const int b = blockIdx.x;
    const int j = threadIdx.x;
    const float4* p = (const float4*)(pooled + (size_t)b * 256);
    const float4* w = (const float4*)(W1 + (size_t)j * 256);
    float s = 0.0f;
    #pragma unroll
    for (int q = 0; q < 64; ++q) {
        float4 pv = p[q];
        float4 wv = w[q];
        s += pv.x * wv.x + pv.y * wv.y + pv.z * wv.z + pv.w * wv.w;
    }
    s += b1[j];
    s = fmaxf(s, 0.0f);
    float v = W2[j] * s;
    #pragma unroll
    for (int off = 32; off; off >>= 1) v += __shfl_down(v, off);
    if (j == 0) out[b] = 1.0f / (1.0f + __expf(-(v + b2[0])));
}

extern "C" void kernel_launch(void* const* d_in, const int* in_sizes, int n_in,
                              void* d_out, int out_size, void* d_ws, size_t ws_size,
                              hipStream_t stream) {
    const int*   x     = (const int*)d_in[0];
    const float* emb   = (const float*)d_in[1];
    const float* Wih_f = (const float*)d_in[2];
    const float* Whh_f = (const float*)d_in[3];
    const float* bih_f = (const float*)d_in[4];
    const float* bhh_f = (const float*)d_in[5];
    const float* Wih_b = (const float*)d_in[6];
    const float* Whh_b = (const float*)d_in[7];
    const float* bih_b = (const float*)d_in[8];
    const float* bhh_b = (const float*)d_in[9];
    const float* W1    = (const float*)d_in[10];
    const float* b1    = (const float*)d_in[11];
    const float* W2    = (const float*)d_in[12];
    const float* b2    = (const float*)d_in[13];
    float* out    = (float*)d_out;
    float* pooled = (float*)d_ws;   // 128*256 f32 = 128 KB

    hipLaunchKernelGGL(bilstm_kernel, dim3(256), dim3(512), 0, stream,
                       x, emb, Wih_f, Whh_f, bih_f, bhh_f,
                       Wih_b, Whh_b, bih_b, bhh_b, pooled);
    hipLaunchKernelGGL(mlp_kernel, dim3(128), dim3(64), 0, stream,
                       pooled, W1, b1, W2, b2, out);
}

// Round 2
// 624.285 us; speedup vs baseline: 1.0023x; 1.0023x over previous
//
#include <hip/hip_runtime.h>
#include <hip/hip_fp16.h>

#define TT 512
#define BB 128
#define EE 128
#define HH 128
#define GG 512  // 4*H

typedef _Float16 half2_t __attribute__((ext_vector_type(2)));

__device__ __forceinline__ half2_t as_h2(unsigned int u) {
    return __builtin_bit_cast(half2_t, u);
}

__device__ __forceinline__ half2_t pack2(float x, float y) {
    half2_t r;
    r.x = (_Float16)x;
    r.y = (_Float16)y;
    return r;
}

__device__ __forceinline__ float fdot2(half2_t a, half2_t b, float c) {
#if __has_builtin(__builtin_amdgcn_fdot2)
    return __builtin_amdgcn_fdot2(a, b, c, false);
#else
    return c + (float)a.x * (float)b.x + (float)a.y * (float)b.y;
#endif
}

__device__ __forceinline__ float sigmoidf_fast(float x) {
    return 1.0f / (1.0f + __expf(-x));
}
__device__ __forceinline__ float tanhf_fast(float x) {
    return 2.0f / (1.0f + __expf(-2.0f * x)) - 1.0f;
}

// One block per (direction, batch element). 512 threads; thread g owns gate
// row g of Wih and Whh in packed-f16 registers (64+64 half2 = 128 VGPRs).
// __launch_bounds__(512,1): a 512-thread block forces 2 waves/EU -> 256-VGPR
// cap, so the 128 weight regs live in real VGPRs (launch_bounds(512,2) capped
// at 128 VGPRs and forced AGPR/scratch churn -> 595us, VALUBusy inflated).
__global__ __launch_bounds__(512, 1) void bilstm_kernel(
    const int* __restrict__ x, const float* __restrict__ emb,
    const float* __restrict__ Wih_f, const float* __restrict__ Whh_f,
    const float* __restrict__ bih_f, const float* __restrict__ bhh_f,
    const float* __restrict__ Wih_b, const float* __restrict__ Whh_b,
    const float* __restrict__ bih_b, const float* __restrict__ bhh_b,
    float* __restrict__ pooled)
{
    const int tid = threadIdx.x;
    const int blk = blockIdx.x;
    const int b   = blk & (BB - 1);
    const int dir = blk >> 7;   // 0 = forward, 1 = backward

    const float* Wih = dir ? Wih_b : Wih_f;
    const float* Whh = dir ? Whh_b : Whh_f;
    const float* bih = dir ? bih_b : bih_f;
    const float* bhh = dir ? bhh_b : bhh_f;

    __shared__ __align__(16) _Float16 e_sm[2][EE];
    __shared__ __align__(16) _Float16 h_sm[HH];
    __shared__ float gates_sm[GG];
    __shared__ int   x_sm[TT];

    // ---- load this thread's weight rows into packed-f16 registers ----
    half2_t wih[64], whh[64];
    {
        const float4* wr = (const float4*)(Wih + (size_t)tid * EE);
        const float4* hr = (const float4*)(Whh + (size_t)tid * EE);
        #pragma unroll
        for (int q = 0; q < 32; ++q) {
            float4 a = wr[q];
            wih[2*q]   = pack2(a.x, a.y);
            wih[2*q+1] = pack2(a.z, a.w);
        }
        #pragma unroll
        for (int q = 0; q < 32; ++q) {
            float4 a = hr[q];
            whh[2*q]   = pack2(a.x, a.y);
            whh[2*q+1] = pack2(a.z, a.w);
        }
    }
    const float bias = bih[tid] + bhh[tid];

    // token ids for this batch row
    x_sm[tid] = x[(size_t)b * TT + tid];
    __syncthreads();

    // stage e for first step; init h = 0
    if (tid < HH) {
        h_sm[tid] = (_Float16)0.0f;
    } else if (tid < 2 * HH) {
        int t0  = dir ? (TT - 1) : 0;
        int id0 = x_sm[t0];
        e_sm[0][tid - HH] = (_Float16)emb[(size_t)id0 * EE + (tid - HH)];
    }
    __syncthreads();

    float c = 0.0f, hmax = -1e30f;

    for (int t = 0; t < TT; ++t) {
        const int buf = t & 1;

        // threads 128..255 prefetch next timestep's embedding row
        // (global-load latency hidden under the dot loop)
        float epre = 0.0f;
        if (tid >= HH && tid < 2 * HH) {
            int tn  = (t + 1 < TT) ? (t + 1) : t;
            int tp  = dir ? (TT - 1 - tn) : tn;
            int idn = x_sm[tp];
            epre = emb[(size_t)idn * EE + (tid - HH)];
        }

        // ---- two 128-length dot products via v_dot2_f32_f16 ----
        const uint4* ev = (const uint4*)e_sm[buf];
        const uint4* hv = (const uint4*)h_sm;
        float a0 = 0.0f, a1 = 0.0f, a2 = 0.0f, a3 = 0.0f;
        #pragma unroll
        for (int q = 0; q < 16; ++q) {
            uint4 e4 = ev[q];
            uint4 h4 = hv[q];
            a0 = fdot2(as_h2(e4.x), wih[4*q+0], a0);
            a1 = fdot2(as_h2(e4.y), wih[4*q+1], a1);
            a0 = fdot2(as_h2(e4.z), wih[4*q+2], a0);
            a1 = fdot2(as_h2(e4.w), wih[4*q+3], a1);
            a2 = fdot2(as_h2(h4.x), whh[4*q+0], a2);
            a3 = fdot2(as_h2(h4.y), whh[4*q+1], a3);
            a2 = fdot2(as_h2(h4.z), whh[4*q+2], a2);
            a3 = fdot2(as_h2(h4.w), whh[4*q+3], a3);
        }
        float pre = bias + ((a0 + a1) + (a2 + a3));

        // PyTorch gate order: [i | f | g | o]; sigmoid except g -> tanh.
        // Branch is wave-uniform (waves 4,5 take tanh).
        float act;
        if (tid < 256 || tid >= 384) act = sigmoidf_fast(pre);
        else                         act = tanhf_fast(pre);
        gates_sm[tid] = act;
        __syncthreads();

        if (tid < HH) {
            float ig = gates_sm[tid];
            float fg = gates_sm[HH + tid];
            float gg = gates_sm[2*HH + tid];
            float og = gates_sm[3*HH + tid];
            c = fg * c + ig * gg;
            float hval = og * tanhf_fast(c);
            hmax = fmaxf(hmax, hval);
            h_sm[tid] = (_Float16)hval;
        } else if (tid < 2 * HH) {
            e_sm[1 - buf][tid - HH] = (_Float16)epre;
        }
        __syncthreads();
    }

    if (tid < HH) {
        pooled[(size_t)b * 256 + dir * HH + tid] = hmax;
    }
}

// pooled (128,256) -> relu(W1 @ . + b1) -> sigmoid(W2 @ . + b2) -> out (128,1)
__global__ __launch_bounds__(64) void mlp_kernel(
    const float* __restrict__ pooled, const float* __restrict__ W1,
    const float* __restrict__ b1, const float* __restrict__ W2,
    const float* __restrict__ b2, float* __restrict__ out)
{
    const int b = blockIdx.x;
    const int j = threadIdx.x;
    const float4* p = (const float4*)(pooled + (size_t)b * 256);
    const float4* w = (const float4*)(W1 + (size_t)j * 256);
    float s = 0.0f;
    #pragma unroll
    for (int q = 0; q < 64; ++q) {
        float4 pv = p[q];
        float4 wv = w[q];
        s += pv.x * wv.x + pv.y * wv.y + pv.z * wv.z + pv.w * wv.w;
    }
    s += b1[j];
    s = fmaxf(s, 0.0f);
    float v = W2[j] * s;
    #pragma unroll
    for (int off = 32; off; off >>= 1) v += __shfl_down(v, off);
    if (j == 0) out[b] = 1.0f / (1.0f + __expf(-(v + b2[0])));
}

extern "C" void kernel_launch(void* const* d_in, const int* in_sizes, int n_in,
                              void* d_out, int out_size, void* d_ws, size_t ws_size,
                              hipStream_t stream) {
    const int*   x     = (const int*)d_in[0];
    const float* emb   = (const float*)d_in[1];
    const float* Wih_f = (const float*)d_in[2];
    const float* Whh_f = (const float*)d_in[3];
    const float* bih_f = (const float*)d_in[4];
    const float* bhh_f = (const float*)d_in[5];
    const float* Wih_b = (const float*)d_in[6];
    const float* Whh_b = (const float*)d_in[7];
    const float* bih_b = (const float*)d_in[8];
    const float* bhh_b = (const float*)d_in[9];
    const float* W1    = (const float*)d_in[10];
    const float* b1    = (const float*)d_in[11];
    const float* W2    = (const float*)d_in[12];
    const float* b2    = (const float*)d_in[13];
    float* out    = (float*)d_out;
    float* pooled = (float*)d_ws;   // 128*256 f32 = 128 KB

    hipLaunchKernelGGL(bilstm_kernel, dim3(256), dim3(512), 0, stream,
                       x, emb, Wih_f, Whh_f, bih_f, bhh_f,
                       Wih_b, Whh_b, bih_b, bhh_b, pooled);
    hipLaunchKernelGGL(mlp_kernel, dim3(128), dim3(64), 0, stream,
                       pooled, W1, b1, W2, b2, out);
}